// Round 1
// baseline (490.579 us; speedup 1.0000x reference)
//
#include <hip/hip_runtime.h>
#include <math.h>

#define S 1024
#define LOG2S 10
#define RADIUS 512
#define NIMG 32   // 16 "output" images then 16 "target" images

__device__ __forceinline__ float2 cmul(float2 a, float2 b) {
    return make_float2(a.x * b.x - a.y * b.y, a.x * b.y + a.y * b.x);
}

__global__ void zero_rad_kernel(float* rad) {
    int i = blockIdx.x * blockDim.x + threadIdx.x;
    if (i < NIMG * RADIUS) rad[i] = 0.0f;
}

// ---------------------------------------------------------------------------
// Pass A: 1024-pt row FFT, one workgroup per (image, row).
// In-place radix-2 DIF in LDS; output stays in bit-reversed frequency order.
// W[img][y][px] ; true frequency u = bitrev10(px).
// ---------------------------------------------------------------------------
__global__ __launch_bounds__(256)
void fft_rows(const float* __restrict__ outp, const float* __restrict__ tgtp,
              float2* __restrict__ W, int imgBase) {
    __shared__ float2 data[S];
    __shared__ float2 tw[S / 2];
    const int t = threadIdx.x;
    const int y = blockIdx.x;
    const int i = blockIdx.y;        // image within chunk
    const int g = imgBase + i;       // global image 0..31

    const float* src = (g < 16 ? outp : tgtp)
                       + (size_t)(g & 15) * S * S + (size_t)y * S;

    for (int j = t; j < S / 2; j += 256) {
        float ang = -6.283185307179586f * (float)j / (float)S;
        float sv, cv;
        sincosf(ang, &sv, &cv);
        tw[j] = make_float2(cv, sv);   // exp(-2*pi*i*j/S)
    }
    #pragma unroll
    for (int k = 0; k < S / 256; ++k) {
        int p = t + k * 256;
        data[p] = make_float2(src[p], 0.0f);
    }
    __syncthreads();

    for (int s = 0; s < LOG2S; ++s) {
        const int h = S >> (s + 1);
        #pragma unroll
        for (int k = 0; k < 2; ++k) {
            int bt = t + k * 256;                       // butterfly id 0..511
            int j = bt & (h - 1);
            int base = ((bt >> (LOG2S - 1 - s)) << (LOG2S - s)) + j;
            float2 a = data[base];
            float2 b = data[base + h];
            data[base] = make_float2(a.x + b.x, a.y + b.y);
            float2 d = make_float2(a.x - b.x, a.y - b.y);
            data[base + h] = cmul(d, tw[j << s]);
        }
        __syncthreads();
    }

    float2* dst = W + ((size_t)i * S + y) * S;
    #pragma unroll
    for (int k = 0; k < S / 256; ++k) {
        int p = t + k * 256;
        dst[p] = data[p];
    }
}

// ---------------------------------------------------------------------------
// Pass B: 1024-pt column FFTs (NC columns per workgroup) + |F|^2 radial bin.
// Column px holds true u = bitrev10(px); output position py holds v = bitrev10(py).
// ---------------------------------------------------------------------------
#define NC 4
#define CSTRIDE 1026   // pad to de-stride LDS banks

__global__ __launch_bounds__(512)
void fft_cols_bin(const float2* __restrict__ W, float* __restrict__ rad, int imgBase) {
    __shared__ float2 col[NC * CSTRIDE];
    __shared__ float2 tw[S / 2];
    __shared__ float bins[RADIUS + 1];
    const int t = threadIdx.x;
    const int x0 = blockIdx.x * NC;
    const int i = blockIdx.y;
    const int g = imgBase + i;

    for (int j = t; j < S / 2; j += 512) {
        float ang = -6.283185307179586f * (float)j / (float)S;
        float sv, cv;
        sincosf(ang, &sv, &cv);
        tw[j] = make_float2(cv, sv);
    }
    for (int j = t; j <= RADIUS; j += 512) bins[j] = 0.0f;

    const float2* Wimg = W + (size_t)i * S * S;
    #pragma unroll
    for (int k = 0; k < (S * NC) / 512; ++k) {
        int f = t + k * 512;
        int yy = f >> 2, c = f & 3;                    // 32B contiguous per row
        col[c * CSTRIDE + yy] = Wimg[(size_t)yy * S + x0 + c];
    }
    __syncthreads();

    for (int s = 0; s < LOG2S; ++s) {
        const int h = S >> (s + 1);
        #pragma unroll
        for (int k = 0; k < (NC * S / 2) / 512; ++k) { // 4 butterflies/thread
            int f = t + k * 512;
            int c = f >> 9;                            // 512 butterflies per column
            int bt = f & 511;
            int j = bt & (h - 1);
            int base = c * CSTRIDE + ((bt >> (LOG2S - 1 - s)) << (LOG2S - s)) + j;
            float2 a = col[base];
            float2 b = col[base + h];
            col[base] = make_float2(a.x + b.x, a.y + b.y);
            float2 d = make_float2(a.x - b.x, a.y - b.y);
            col[base + h] = cmul(d, tw[j << s]);
        }
        __syncthreads();
    }

    #pragma unroll
    for (int k = 0; k < (S * NC) / 512; ++k) {
        int f = t + k * 512;
        int c = f >> LOG2S;
        int py = f & (S - 1);
        int px = x0 + c;
        int u = (int)(__brev((unsigned)px) >> 22);
        int v = (int)(__brev((unsigned)py) >> 22);
        float cu = (u < S / 2) ? (u + 0.5f) : (u - (float)S + 0.5f);
        float cv2 = (v < S / 2) ? (v + 0.5f) : (v - (float)S + 0.5f);
        float2 z = col[c * CSTRIDE + py];
        float p = z.x * z.x + z.y * z.y;
        float dd = sqrtf(cu * cu + cv2 * cv2);
        int bin = (dd < (float)RADIUS) ? (int)dd : RADIUS;  // 512 = overflow (dropped)
        atomicAdd(&bins[bin], p);
    }
    __syncthreads();
    for (int j = t; j < RADIUS; j += 512) {
        atomicAdd(&rad[(size_t)g * RADIUS + j], bins[j]);
    }
}

// ---------------------------------------------------------------------------
// Final: loss = mean(|rad_out - rad_tgt|) / S^2
// ---------------------------------------------------------------------------
__global__ __launch_bounds__(256)
void final_loss(const float* __restrict__ rad, float* __restrict__ out) {
    __shared__ float red[256];
    const int t = threadIdx.x;
    float acc = 0.0f;
    for (int i = t; i < 16 * RADIUS; i += 256) {
        int b = i >> 9;
        int r = i & (RADIUS - 1);
        float o = rad[(size_t)b * RADIUS + r];
        float gg = rad[(size_t)(b + 16) * RADIUS + r];
        acc += fabsf(o - gg);
    }
    red[t] = acc;
    __syncthreads();
    for (int off = 128; off > 0; off >>= 1) {
        if (t < off) red[t] += red[t + off];
        __syncthreads();
    }
    if (t == 0) {
        out[0] = red[0] / ((float)S * (float)S) / (16.0f * (float)RADIUS);
    }
}

extern "C" void kernel_launch(void* const* d_in, const int* in_sizes, int n_in,
                              void* d_out, int out_size, void* d_ws, size_t ws_size,
                              hipStream_t stream) {
    const float* outp = (const float*)d_in[0];
    const float* tgtp = (const float*)d_in[1];
    float* dout = (float*)d_out;

    char* ws = (char*)d_ws;
    float* rad = (float*)ws;                         // 32*512 floats = 64 KB
    float2* W = (float2*)(ws + 65536);               // complex intermediate
    const size_t perImg = (size_t)S * S * sizeof(float2);   // 8 MB / image
    size_t avail = (ws_size > 65536) ? (ws_size - 65536) : 0;
    int chunk = (int)(avail / perImg);
    if (chunk > NIMG) chunk = NIMG;
    if (chunk < 1) chunk = 1;                        // hope ws is large enough

    zero_rad_kernel<<<(NIMG * RADIUS + 255) / 256, 256, 0, stream>>>(rad);

    for (int base = 0; base < NIMG; base += chunk) {
        int c = (NIMG - base < chunk) ? (NIMG - base) : chunk;
        fft_rows<<<dim3(S, c), 256, 0, stream>>>(outp, tgtp, W, base);
        fft_cols_bin<<<dim3(S / NC, c), 512, 0, stream>>>(W, rad, base);
    }

    final_loss<<<1, 256, 0, stream>>>(rad, dout);
}

// Round 2
// 385.853 us; speedup vs baseline: 1.2714x; 1.2714x over previous
//
#include <hip/hip_runtime.h>
#include <math.h>

#define S 1024
#define RADIUS 512
#define NIMG 32   // 16 "output" images then 16 "target" images

// ---------------------------------------------------------------------------
// Complex helpers
// ---------------------------------------------------------------------------
__device__ __forceinline__ float2 cmul(float2 a, float2 b) {
    return make_float2(a.x * b.x - a.y * b.y, a.x * b.y + a.y * b.x);
}
__device__ __forceinline__ float2 cadd(float2 a, float2 b) { return make_float2(a.x + b.x, a.y + b.y); }
__device__ __forceinline__ float2 csub(float2 a, float2 b) { return make_float2(a.x - b.x, a.y - b.y); }

// W_16^k = exp(-2*pi*i*k/16), k = 0..7
__device__ const float2 C16[8] = {
    {1.0f, 0.0f},
    {0.92387953251128674f, -0.38268343236508978f},
    {0.70710678118654757f, -0.70710678118654746f},
    {0.38268343236508984f, -0.92387953251128674f},
    {0.0f, -1.0f},
    {-0.38268343236508973f, -0.92387953251128674f},
    {-0.70710678118654746f, -0.70710678118654757f},
    {-0.92387953251128663f, -0.38268343236508989f},
};

// 4 radix-2 DIF stages over 16 register-resident elements.
// Element r[j] corresponds to global index n = stride*j + off; entering twiddle
// base T = W_1024^{(n mod h0) contribution} such that stage s uses T^(2^s)*C16[mu<<s].
__device__ __forceinline__ void fft16(float2 r[16], float2 T) {
    float2 tc[8];
    // stage jd=8
    #pragma unroll
    for (int u = 0; u < 8; ++u) tc[u] = cmul(T, C16[u]);
    #pragma unroll
    for (int u = 0; u < 8; ++u) {
        float2 a = r[u], b = r[u + 8];
        r[u] = cadd(a, b);
        r[u + 8] = cmul(csub(a, b), tc[u]);
    }
    T = cmul(T, T);
    // stage jd=4
    #pragma unroll
    for (int u = 0; u < 4; ++u) tc[u] = cmul(T, C16[2 * u]);
    #pragma unroll
    for (int g = 0; g < 2; ++g) {
        #pragma unroll
        for (int u = 0; u < 4; ++u) {
            int lo = g * 8 + u;
            float2 a = r[lo], b = r[lo + 4];
            r[lo] = cadd(a, b);
            r[lo + 4] = cmul(csub(a, b), tc[u]);
        }
    }
    T = cmul(T, T);
    // stage jd=2
    #pragma unroll
    for (int u = 0; u < 2; ++u) tc[u] = cmul(T, C16[4 * u]);
    #pragma unroll
    for (int g = 0; g < 4; ++g) {
        #pragma unroll
        for (int u = 0; u < 2; ++u) {
            int lo = g * 4 + u;
            float2 a = r[lo], b = r[lo + 2];
            r[lo] = cadd(a, b);
            r[lo + 2] = cmul(csub(a, b), tc[u]);
        }
    }
    T = cmul(T, T);
    // stage jd=1
    #pragma unroll
    for (int g = 0; g < 8; ++g) {
        int lo = g * 2;
        float2 a = r[lo], b = r[lo + 1];
        r[lo] = cadd(a, b);
        r[lo + 1] = cmul(csub(a, b), T);
    }
}

// Last 2 DIF stages (h=2, h=1) via quad shuffles; thread's c = tau&3 = n bits 0-1.
__device__ __forceinline__ void fft_last2(float2 r[16], int c) {
    #pragma unroll
    for (int m = 0; m < 16; ++m) {
        float vx = __shfl_xor(r[m].x, 2, 64);
        float vy = __shfl_xor(r[m].y, 2, 64);
        if (c & 2) {
            float dx = vx - r[m].x, dy = vy - r[m].y;
            if (c & 1) { r[m].x = dy; r[m].y = -dx; }   // *( -i )
            else       { r[m].x = dx; r[m].y = dy; }
        } else {
            r[m].x += vx; r[m].y += vy;
        }
    }
    #pragma unroll
    for (int m = 0; m < 16; ++m) {
        float vx = __shfl_xor(r[m].x, 1, 64);
        float vy = __shfl_xor(r[m].y, 1, 64);
        if (c & 1) { r[m].x = vx - r[m].x; r[m].y = vy - r[m].y; }
        else       { r[m].x += vx; r[m].y += vy; }
    }
}

// XOR-swizzled LDS address: conflict-free for both n=64j+tau (j fixed) and
// n=64b+4m+c (m fixed) access patterns.
__device__ __forceinline__ int A1x(int n) {
    int j = n >> 6;
    return (n & ~63) | ((n & 63) ^ (j << 2));
}

__global__ void zero_rad_kernel(float* rad) {
    int i = blockIdx.x * blockDim.x + threadIdx.x;
    if (i < NIMG * RADIUS) rad[i] = 0.0f;
}

// ---------------------------------------------------------------------------
// Pass A: row FFTs. Block = 4 waves, one 1024-pt FFT per wave.
// Output in DIF position order (freq = bitrev10(pos)).
// ---------------------------------------------------------------------------
__global__ __launch_bounds__(256)
void fft_rows(const float* __restrict__ outp, const float* __restrict__ tgtp,
              float2* __restrict__ W, int imgBase) {
    __shared__ float2 buf[4 * 1024];     // 32 KB, one 1024-slot buffer per wave
    const int t = threadIdx.x;
    const int w = t >> 6, tau = t & 63;
    const int y = blockIdx.x * 4 + w;
    const int g = imgBase + blockIdx.y;
    const float* src = (g < 16 ? outp : tgtp)
                       + (size_t)(g & 15) * S * S + (size_t)y * S;

    float2 r[16];
    #pragma unroll
    for (int j = 0; j < 16; ++j) r[j] = make_float2(src[64 * j + tau], 0.0f);

    float2 T;
    { float sv, cv; sincosf(-6.283185307179586f * (float)tau / 1024.0f, &sv, &cv); T = make_float2(cv, sv); }
    fft16(r, T);

    float2* mybuf = buf + (w << 10);
    #pragma unroll
    for (int j = 0; j < 16; ++j) mybuf[A1x(64 * j + tau)] = r[j];
    __syncthreads();
    const int b = tau >> 2, c = tau & 3;
    #pragma unroll
    for (int m = 0; m < 16; ++m) r[m] = mybuf[(b << 6) + 4 * (m ^ b) + c];

    { float sv, cv; sincosf(-6.283185307179586f * (float)c / 64.0f, &sv, &cv); T = make_float2(cv, sv); }
    fft16(r, T);
    fft_last2(r, c);

    float2* dst = W + ((size_t)blockIdx.y * S + y) * S;
    #pragma unroll
    for (int m = 0; m < 16; ++m) dst[(b << 6) + 4 * m + c] = r[m];
}

// ---------------------------------------------------------------------------
// Pass B: column FFTs + |F|^2 radial binning. Block = 8 waves = 8 columns.
// Staging tile reads 64 B-aligned row segments (full coalescing).
// Bin histogram aliases the staging buffer (LDS budget = 64 KB exactly).
// ---------------------------------------------------------------------------
__global__ __launch_bounds__(512)
void fft_cols_bin(const float2* __restrict__ Wm, float* __restrict__ rad, int imgBase) {
    __shared__ float2 buf[8 * 1024];     // 64 KB; bins alias after last read
    float* bins = (float*)buf;           // [RADIUS+1]
    const int t = threadIdx.x;
    const int w = t >> 6, tau = t & 63;
    const int px0 = blockIdx.x * 8;
    const int i = blockIdx.y, g = imgBase + i;

    // stage: per instr, 8 rows x 8 cols -> 64 B contiguous per row segment
    const float2* Wimg = Wm + (size_t)i * S * S;
    #pragma unroll
    for (int k = 0; k < 16; ++k) {
        int f = t + k * 512;
        int yy = f >> 3, cc = f & 7;
        buf[(cc << 10) + (A1x(yy) ^ cc)] = Wimg[(size_t)yy * S + px0 + cc];
    }
    __syncthreads();

    float2 r[16];
    float2* mybuf = buf + (w << 10);
    #pragma unroll
    for (int j = 0; j < 16; ++j) r[j] = mybuf[A1x(64 * j + tau) ^ w];
    float2 T;
    { float sv, cv; sincosf(-6.283185307179586f * (float)tau / 1024.0f, &sv, &cv); T = make_float2(cv, sv); }
    fft16(r, T);
    #pragma unroll
    for (int j = 0; j < 16; ++j) mybuf[A1x(64 * j + tau) ^ w] = r[j];
    __syncthreads();
    const int b = tau >> 2, c = tau & 3;
    #pragma unroll
    for (int m = 0; m < 16; ++m) r[m] = mybuf[((b << 6) + 4 * (m ^ b) + c) ^ w];
    __syncthreads();                     // all reads of buf done -> safe to alias bins

    for (int j = t; j <= RADIUS; j += 512) bins[j] = 0.0f;
    __syncthreads();

    { float sv, cv; sincosf(-6.283185307179586f * (float)c / 64.0f, &sv, &cv); T = make_float2(cv, sv); }
    fft16(r, T);
    fft_last2(r, c);

    // binning: column freq u fixed per wave; row freq v = bitrev10(position)
    int px = px0 + w;
    int u = (int)(__brev((unsigned)px) >> 22);
    float cu = (u < S / 2) ? (u + 0.5f) : (u - (float)S + 0.5f);
    #pragma unroll
    for (int m = 0; m < 16; ++m) {
        int n = (b << 6) + 4 * m + c;
        int v = (int)(__brev((unsigned)n) >> 22);
        float cvv = (v < S / 2) ? (v + 0.5f) : (v - (float)S + 0.5f);
        float p = r[m].x * r[m].x + r[m].y * r[m].y;
        float dd = sqrtf(cu * cu + cvv * cvv);
        int bin = (dd < (float)RADIUS) ? (int)dd : RADIUS;  // RADIUS = dropped
        atomicAdd(&bins[bin], p);
    }
    __syncthreads();
    for (int j = t; j < RADIUS; j += 512) {
        atomicAdd(&rad[(size_t)g * RADIUS + j], bins[j]);
    }
}

// ---------------------------------------------------------------------------
// Final: loss = mean(|rad_out - rad_tgt|) / S^2
// ---------------------------------------------------------------------------
__global__ __launch_bounds__(256)
void final_loss(const float* __restrict__ rad, float* __restrict__ out) {
    __shared__ float red[256];
    const int t = threadIdx.x;
    float acc = 0.0f;
    for (int i = t; i < 16 * RADIUS; i += 256) {
        int bb = i >> 9;
        int rr = i & (RADIUS - 1);
        float o = rad[(size_t)bb * RADIUS + rr];
        float gg = rad[(size_t)(bb + 16) * RADIUS + rr];
        acc += fabsf(o - gg);
    }
    red[t] = acc;
    __syncthreads();
    for (int off = 128; off > 0; off >>= 1) {
        if (t < off) red[t] += red[t + off];
        __syncthreads();
    }
    if (t == 0) {
        out[0] = red[0] / ((float)S * (float)S) / (16.0f * (float)RADIUS);
    }
}

extern "C" void kernel_launch(void* const* d_in, const int* in_sizes, int n_in,
                              void* d_out, int out_size, void* d_ws, size_t ws_size,
                              hipStream_t stream) {
    const float* outp = (const float*)d_in[0];
    const float* tgtp = (const float*)d_in[1];
    float* dout = (float*)d_out;

    char* ws = (char*)d_ws;
    float* rad = (float*)ws;                         // 32*512 floats = 64 KB
    float2* W = (float2*)(ws + 65536);               // complex intermediate
    const size_t perImg = (size_t)S * S * sizeof(float2);   // 8 MB / image
    size_t avail = (ws_size > 65536) ? (ws_size - 65536) : 0;
    int chunk = (int)(avail / perImg);
    if (chunk > NIMG) chunk = NIMG;
    if (chunk < 1) chunk = 1;

    zero_rad_kernel<<<(NIMG * RADIUS + 255) / 256, 256, 0, stream>>>(rad);

    for (int base = 0; base < NIMG; base += chunk) {
        int c = (NIMG - base < chunk) ? (NIMG - base) : chunk;
        fft_rows<<<dim3(S / 4, c), 256, 0, stream>>>(outp, tgtp, W, base);
        fft_cols_bin<<<dim3(S / 8, c), 512, 0, stream>>>(W, rad, base);
    }

    final_loss<<<1, 256, 0, stream>>>(rad, dout);
}

// Round 3
// 242.241 us; speedup vs baseline: 2.0252x; 1.5928x over previous
//
#include <hip/hip_runtime.h>
#include <math.h>

#define S 1024
#define RADIUS 512
#define NIMG 32   // 16 "output" images then 16 "target" images

// ---------------------------------------------------------------------------
// Complex helpers
// ---------------------------------------------------------------------------
__device__ __forceinline__ float2 cmul(float2 a, float2 b) {
    return make_float2(a.x * b.x - a.y * b.y, a.x * b.y + a.y * b.x);
}
__device__ __forceinline__ float2 cadd(float2 a, float2 b) { return make_float2(a.x + b.x, a.y + b.y); }
__device__ __forceinline__ float2 csub(float2 a, float2 b) { return make_float2(a.x - b.x, a.y - b.y); }

// W_16^k, k=0..7
__device__ const float2 C16[8] = {
    {1.0f, 0.0f},
    {0.92387953251128674f, -0.38268343236508978f},
    {0.70710678118654757f, -0.70710678118654746f},
    {0.38268343236508984f, -0.92387953251128674f},
    {0.0f, -1.0f},
    {-0.38268343236508973f, -0.92387953251128674f},
    {-0.70710678118654746f, -0.70710678118654757f},
    {-0.92387953251128663f, -0.38268343236508989f},
};
// W_8^k, k=0..3
__device__ const float2 C8T[4] = {
    {1.0f, 0.0f},
    {0.70710678118654757f, -0.70710678118654746f},
    {0.0f, -1.0f},
    {-0.70710678118654746f, -0.70710678118654757f},
};
// W_128^{bitrev3(m)} for m=0..7 (combine-step twiddle factors)
__device__ const float2 C128R[8] = {
    {1.0f, 0.0f},
    {0.98078528040323044f, -0.19509032201612825f},   // W128^4
    {0.99518472667219693f, -0.09801714032956060f},   // W128^2
    {0.95694033573220886f, -0.29028467725446233f},   // W128^6
    {0.99879545620517241f, -0.04906767432741801f},   // W128^1
    {0.97003125319454397f, -0.24298017990326390f},   // W128^5
    {0.98917650996478101f, -0.14673047445536175f},   // W128^3
    {0.94154406518302081f, -0.33688985339222005f},   // W128^7
};

// 4 radix-2 DIF stages over 16 register elements (n = 64j + tau, T = base twiddle)
__device__ __forceinline__ void fft16(float2 r[16], float2 T) {
    float2 tc[8];
    #pragma unroll
    for (int u = 0; u < 8; ++u) tc[u] = cmul(T, C16[u]);
    #pragma unroll
    for (int u = 0; u < 8; ++u) {
        float2 a = r[u], b = r[u + 8];
        r[u] = cadd(a, b);
        r[u + 8] = cmul(csub(a, b), tc[u]);
    }
    T = cmul(T, T);
    #pragma unroll
    for (int u = 0; u < 4; ++u) tc[u] = cmul(T, C16[2 * u]);
    #pragma unroll
    for (int g = 0; g < 2; ++g)
        #pragma unroll
        for (int u = 0; u < 4; ++u) {
            int lo = g * 8 + u;
            float2 a = r[lo], b = r[lo + 4];
            r[lo] = cadd(a, b);
            r[lo + 4] = cmul(csub(a, b), tc[u]);
        }
    T = cmul(T, T);
    #pragma unroll
    for (int u = 0; u < 2; ++u) tc[u] = cmul(T, C16[4 * u]);
    #pragma unroll
    for (int g = 0; g < 4; ++g)
        #pragma unroll
        for (int u = 0; u < 2; ++u) {
            int lo = g * 4 + u;
            float2 a = r[lo], b = r[lo + 2];
            r[lo] = cadd(a, b);
            r[lo + 2] = cmul(csub(a, b), tc[u]);
        }
    T = cmul(T, T);
    #pragma unroll
    for (int g = 0; g < 8; ++g) {
        int lo = g * 2;
        float2 a = r[lo], b = r[lo + 1];
        r[lo] = cadd(a, b);
        r[lo + 1] = cmul(csub(a, b), T);
    }
}

// 3 radix-2 DIF stages over 8 register elements
__device__ __forceinline__ void fft8(float2 r[8], float2 T) {
    float2 tc[4];
    #pragma unroll
    for (int u = 0; u < 4; ++u) tc[u] = cmul(T, C8T[u]);
    #pragma unroll
    for (int u = 0; u < 4; ++u) {
        float2 a = r[u], b = r[u + 4];
        r[u] = cadd(a, b);
        r[u + 4] = cmul(csub(a, b), tc[u]);
    }
    T = cmul(T, T);
    #pragma unroll
    for (int u = 0; u < 2; ++u) tc[u] = cmul(T, C8T[2 * u]);
    #pragma unroll
    for (int g = 0; g < 2; ++g)
        #pragma unroll
        for (int u = 0; u < 2; ++u) {
            int lo = g * 4 + u;
            float2 a = r[lo], b = r[lo + 2];
            r[lo] = cadd(a, b);
            r[lo + 2] = cmul(csub(a, b), tc[u]);
        }
    T = cmul(T, T);
    #pragma unroll
    for (int g = 0; g < 4; ++g) {
        int lo = g * 2;
        float2 a = r[lo], b = r[lo + 1];
        r[lo] = cadd(a, b);
        r[lo + 1] = cmul(csub(a, b), T);
    }
}

// Last 2 DIF stages (1024-pt): shuffles across c = tau&3
__device__ __forceinline__ void fft_last2(float2 r[16], int c) {
    #pragma unroll
    for (int m = 0; m < 16; ++m) {
        float vx = __shfl_xor(r[m].x, 2, 64);
        float vy = __shfl_xor(r[m].y, 2, 64);
        if (c & 2) {
            float dx = vx - r[m].x, dy = vy - r[m].y;
            if (c & 1) { r[m].x = dy; r[m].y = -dx; }
            else       { r[m].x = dx; r[m].y = dy; }
        } else {
            r[m].x += vx; r[m].y += vy;
        }
    }
    #pragma unroll
    for (int m = 0; m < 16; ++m) {
        float vx = __shfl_xor(r[m].x, 1, 64);
        float vy = __shfl_xor(r[m].y, 1, 64);
        if (c & 1) { r[m].x = vx - r[m].x; r[m].y = vy - r[m].y; }
        else       { r[m].x += vx; r[m].y += vy; }
    }
}

// Last 3 DIF stages (512-pt): shuffles across lam = tau&7
__device__ __forceinline__ void fft_last3(float2 r[8], int lam) {
    const float R2 = 0.70710678118654757f;
    int k = lam & 3;
    float2 w8;
    w8.x = (k == 0) ? 1.0f : ((k == 1) ? R2 : ((k == 2) ? 0.0f : -R2));
    w8.y = (k == 0) ? 0.0f : ((k == 2) ? -1.0f : -R2);
    #pragma unroll
    for (int m = 0; m < 8; ++m) {
        float vx = __shfl_xor(r[m].x, 4, 64);
        float vy = __shfl_xor(r[m].y, 4, 64);
        if (lam & 4) {
            float2 d = make_float2(vx - r[m].x, vy - r[m].y);
            r[m] = cmul(d, w8);
        } else { r[m].x += vx; r[m].y += vy; }
    }
    #pragma unroll
    for (int m = 0; m < 8; ++m) {
        float vx = __shfl_xor(r[m].x, 2, 64);
        float vy = __shfl_xor(r[m].y, 2, 64);
        if (lam & 2) {
            float dx = vx - r[m].x, dy = vy - r[m].y;
            if (lam & 1) { r[m].x = dy; r[m].y = -dx; }   // * (-i)
            else         { r[m].x = dx; r[m].y = dy; }
        } else { r[m].x += vx; r[m].y += vy; }
    }
    #pragma unroll
    for (int m = 0; m < 8; ++m) {
        float vx = __shfl_xor(r[m].x, 1, 64);
        float vy = __shfl_xor(r[m].y, 1, 64);
        if (lam & 1) { r[m].x = vx - r[m].x; r[m].y = vy - r[m].y; }
        else         { r[m].x += vx; r[m].y += vy; }
    }
}

// Swizzled LDS addr for 1024-pt transpose
__device__ __forceinline__ int A1x(int n) {
    int j = n >> 6;
    return (n & ~63) | ((n & 63) ^ (j << 2));
}

// Full 512-pt FFT for one wave (8 complex per lane, in place).
// Input r[j] = x[64j + tau]; output: r[m] = X at position p = 64*(tau>>3) + 8m + (tau&7),
// freq t = bitrev9(p). buf = wave-private 512-slot LDS.
__device__ __forceinline__ void fft512(float2 r[8], float2* buf, int tau, float2 T1, float2 T2) {
    fft8(r, T1);
    #pragma unroll
    for (int j = 0; j < 8; ++j) buf[(j << 6) | (tau ^ (j << 3))] = r[j];
    const int b3 = tau >> 3, lam = tau & 7;
    #pragma unroll
    for (int m = 0; m < 8; ++m) r[m] = buf[(b3 << 6) | (((m ^ b3) << 3) + lam)];
    fft8(r, T2);
    fft_last3(r, lam);
}

__device__ __forceinline__ int bitrev3(int x) {
    return ((x & 1) << 2) | (x & 2) | ((x >> 2) & 1);
}

__global__ void zero_rad_kernel(float* rad) {
    int i = blockIdx.x * blockDim.x + threadIdx.x;
    if (i < NIMG * RADIUS) rad[i] = 0.0f;
}

// ---------------------------------------------------------------------------
// Pass A: packed row-pair FFTs. Wave w handles rows 2yy, 2yy+1 (yy = bx*8+w).
// Z = FFT(row0 + i*row1), stored TRANSPOSED in natural-u order:
// WpT[u][yy], u=0..1023, yy=0..511.
// ---------------------------------------------------------------------------
__global__ __launch_bounds__(512)
void fft_rows(const float* __restrict__ outp, const float* __restrict__ tgtp,
              float2* __restrict__ WpT, int imgBase) {
    __shared__ float2 buf[8 * 1024];   // 64 KB: one 1024-slot buffer per wave
    const int t = threadIdx.x;
    const int w = t >> 6, tau = t & 63;
    const int yy = blockIdx.x * 8 + w;           // packed row index 0..511
    const int i = blockIdx.y, g = imgBase + i;
    const float* img = (g < 16 ? outp : tgtp) + (size_t)(g & 15) * S * S;
    const float* r0 = img + (size_t)(2 * yy) * S;
    const float* r1 = r0 + S;

    float2 r[16];
    #pragma unroll
    for (int j = 0; j < 16; ++j) r[j] = make_float2(r0[64 * j + tau], r1[64 * j + tau]);

    float2 T;
    { float sv, cv; sincosf(-6.283185307179586f * (float)tau / 1024.0f, &sv, &cv); T = make_float2(cv, sv); }
    fft16(r, T);

    float2* mybuf = buf + (w << 10);
    #pragma unroll
    for (int j = 0; j < 16; ++j) mybuf[A1x(64 * j + tau)] = r[j];
    // wave-private buffer: in-wave DS ordering, no barrier needed
    const int b = tau >> 2, c = tau & 3;
    #pragma unroll
    for (int m = 0; m < 16; ++m) r[m] = mybuf[(b << 6) + 4 * (m ^ b) + c];

    { float sv, cv; sincosf(-6.283185307179586f * (float)c / 64.0f, &sv, &cv); T = make_float2(cv, sv); }
    fft16(r, T);
    fft_last2(r, c);

    // store natural-frequency order into wave buffer (swizzle ^(w<<1) vs banks)
    #pragma unroll
    for (int m = 0; m < 16; ++m) {
        int n = (b << 6) + 4 * m + c;
        int k = (int)(__brev((unsigned)n) >> 22);
        mybuf[k ^ (w << 1)] = r[m];
    }
    __syncthreads();

    // coalesced transposed store: tile [1024 u][8 yy], 64 B per u-segment
    const int yy0 = blockIdx.x * 8;
    float2* dst = WpT + (size_t)i * 512 * 1024;
    #pragma unroll
    for (int q = 0; q < 16; ++q) {
        int idx = q * 512 + t;
        int uu = idx >> 3, wv = idx & 7;
        float2 val = buf[(wv << 10) | (uu ^ (wv << 1))];
        dst[(size_t)uu * 512 + yy0 + wv] = val;
    }
}

// ---------------------------------------------------------------------------
// Pass B: per-wave Hermitian split + two 512-pt column FFTs + combine + bin.
// Wave handles one u in 0..512; reads rows u and (1024-u)&1023 of WpT
// (contiguous), no staging tile. Each |G|^2 binned at (u,v) and mirror.
// ---------------------------------------------------------------------------
__global__ __launch_bounds__(256)
void fft_cols_bin(const float2* __restrict__ WpT, float* __restrict__ rad, int imgBase) {
    __shared__ float2 tbuf[4 * 512];   // 16 KB: 512-slot transpose buffer per wave
    __shared__ float bins[RADIUS + 1];
    const int t = threadIdx.x;
    const int w = t >> 6, tau = t & 63;
    const int i = blockIdx.y, g = imgBase + i;
    const int u = blockIdx.x * 4 + w;            // 0..515 (grid.x = 129)

    for (int j = t; j <= RADIUS; j += 256) bins[j] = 0.0f;
    __syncthreads();

    if (u <= 512) {
        const float2* Wimg = WpT + (size_t)i * 512 * 1024;
        const int mu = (1024 - u) & 1023;
        const float2* rowA = Wimg + (size_t)u * 512;
        const float2* rowM = Wimg + (size_t)mu * 512;

        float2 X0[8], X1[8];
        #pragma unroll
        for (int j = 0; j < 8; ++j) {
            float2 A = rowA[64 * j + tau];
            float2 M = rowM[64 * j + tau];
            X0[j] = make_float2(0.5f * (A.x + M.x), 0.5f * (A.y - M.y));
            X1[j] = make_float2(0.5f * (A.y + M.y), 0.5f * (M.x - A.x));
        }

        float2 T1, T2;
        { float sv, cv; sincosf(-6.283185307179586f * (float)tau / 512.0f, &sv, &cv); T1 = make_float2(cv, sv); }
        const int lam = tau & 7, b3 = tau >> 3;
        { float sv, cv; sincosf(-6.283185307179586f * (float)lam / 64.0f, &sv, &cv); T2 = make_float2(cv, sv); }

        float2* buf = tbuf + (w << 9);
        fft512(X0, buf, tau, T1, T2);   // -> A0 hat
        fft512(X1, buf, tau, T1, T2);   // -> A1 hat

        // combine twiddle W1024^t, t = 64*rev(lam) + 8*rev(m) + rev(b3)
        const int rlam = bitrev3(lam), rb3 = bitrev3(b3);
        float2 Tc;
        { float sv, cv; sincosf(-6.283185307179586f * (float)(64 * rlam + rb3) / 1024.0f, &sv, &cv); Tc = make_float2(cv, sv); }

        const float cu = (u < 512) ? (u + 0.5f) : (u - 1023.5f);
        const int um = 1024 - u;                      // mirror column (u in 1..511)
        const float cum = 0.5f - (float)u;            // its shifted coordinate
        const bool dbl = (u >= 1 && u <= 511);

        #pragma unroll
        for (int m = 0; m < 8; ++m) {
            float2 Wv = cmul(Tc, C128R[m]);
            float2 w1 = cmul(Wv, X1[m]);
            float2 Gp = cadd(X0[m], w1);              // v = tfreq
            float2 Gm = csub(X0[m], w1);              // v = tfreq + 512
            int tf = 64 * rlam + 8 * bitrev3(m) + rb3;
            float p1 = Gp.x * Gp.x + Gp.y * Gp.y;
            float p2 = Gm.x * Gm.x + Gm.y * Gm.y;

            float cv1 = tf + 0.5f;                    // v1 = tf (< 512)
            float cv2 = tf - 511.5f;                  // v2 = tf + 512
            float d1 = sqrtf(cu * cu + cv1 * cv1);
            float d2 = sqrtf(cu * cu + cv2 * cv2);
            if (d1 < (float)RADIUS) atomicAdd(&bins[(int)d1], p1);
            if (d2 < (float)RADIUS) atomicAdd(&bins[(int)d2], p2);
            if (dbl) {
                int v1m = (1024 - tf) & 1023;
                int v2m = 512 - tf;
                float cv1m = (v1m < 512) ? (v1m + 0.5f) : (v1m - 1023.5f);
                float cv2m = (v2m < 512) ? (v2m + 0.5f) : (v2m - 1023.5f);
                float d1m = sqrtf(cum * cum + cv1m * cv1m);
                float d2m = sqrtf(cum * cum + cv2m * cv2m);
                if (d1m < (float)RADIUS) atomicAdd(&bins[(int)d1m], p1);
                if (d2m < (float)RADIUS) atomicAdd(&bins[(int)d2m], p2);
            }
        }
        (void)um;
    }
    __syncthreads();
    for (int j = t; j < RADIUS; j += 256) {
        atomicAdd(&rad[(size_t)g * RADIUS + j], bins[j]);
    }
}

// ---------------------------------------------------------------------------
// Final: loss = mean(|rad_out - rad_tgt|) / S^2
// ---------------------------------------------------------------------------
__global__ __launch_bounds__(256)
void final_loss(const float* __restrict__ rad, float* __restrict__ out) {
    __shared__ float red[256];
    const int t = threadIdx.x;
    float acc = 0.0f;
    for (int i = t; i < 16 * RADIUS; i += 256) {
        int bb = i >> 9;
        int rr = i & (RADIUS - 1);
        float o = rad[(size_t)bb * RADIUS + rr];
        float gg = rad[(size_t)(bb + 16) * RADIUS + rr];
        acc += fabsf(o - gg);
    }
    red[t] = acc;
    __syncthreads();
    for (int off = 128; off > 0; off >>= 1) {
        if (t < off) red[t] += red[t + off];
        __syncthreads();
    }
    if (t == 0) {
        out[0] = red[0] / ((float)S * (float)S) / (16.0f * (float)RADIUS);
    }
}

extern "C" void kernel_launch(void* const* d_in, const int* in_sizes, int n_in,
                              void* d_out, int out_size, void* d_ws, size_t ws_size,
                              hipStream_t stream) {
    const float* outp = (const float*)d_in[0];
    const float* tgtp = (const float*)d_in[1];
    float* dout = (float*)d_out;

    char* ws = (char*)d_ws;
    float* rad = (float*)ws;                          // 64 KB
    float2* WpT = (float2*)(ws + 65536);              // packed transposed spectra
    const size_t perImg = (size_t)512 * 1024 * sizeof(float2);   // 4 MB / image
    size_t avail = (ws_size > 65536) ? (ws_size - 65536) : 0;
    int chunk = (int)(avail / perImg);
    if (chunk > NIMG) chunk = NIMG;
    if (chunk < 1) chunk = 1;

    zero_rad_kernel<<<(NIMG * RADIUS + 255) / 256, 256, 0, stream>>>(rad);

    for (int base = 0; base < NIMG; base += chunk) {
        int c = (NIMG - base < chunk) ? (NIMG - base) : chunk;
        fft_rows<<<dim3(64, c), 512, 0, stream>>>(outp, tgtp, WpT, base);
        fft_cols_bin<<<dim3(129, c), 256, 0, stream>>>(WpT, rad, base);
    }

    final_loss<<<1, 256, 0, stream>>>(rad, dout);
}